// Round 8
// baseline (238.453 us; speedup 1.0000x reference)
//
#include <hip/hip_runtime.h>
#include <math.h>

#define NATOM_FEAT 24   // IPSIN * NWAVE = 3*8
#define PORI 13
#define NW 8
#define HID 128
#define CH 64           // edges staged per LDS chunk
#define CHP (CH + 4)    // padded stride: 68 floats = 17 float4 -> banks spread, 16B aligned
#define SCAN_T 1024

__global__ void zero_k(int* __restrict__ p, int n)
{
    int i = blockIdx.x * blockDim.x + threadIdx.x;
    if (i < n) p[i] = 0;
}

// ---------------- CSR build ----------------
__global__ void csr_count(const int* __restrict__ nl, int* __restrict__ counts, int E)
{
    int e = blockIdx.x * blockDim.x + threadIdx.x;
    if (e < E) atomicAdd(&counts[nl[e]], 1);
}

// scan counts -> rowptr, re-zero counts (reused as fill cursor)
__global__ void csr_scan(int* __restrict__ counts, int* __restrict__ rowptr, int A)
{
    __shared__ int lds[SCAN_T];
    int tid = threadIdx.x;
    int chunk = (A + SCAN_T - 1) / SCAN_T;
    int base = tid * chunk;
    int own = 0;
    for (int i = 0; i < chunk; ++i) {
        int idx = base + i;
        if (idx < A) own += counts[idx];
    }
    lds[tid] = own;
    __syncthreads();
    for (int off = 1; off < SCAN_T; off <<= 1) {
        int v = (tid >= off) ? lds[tid - off] : 0;
        __syncthreads();
        lds[tid] += v;
        __syncthreads();
    }
    int running = lds[tid] - own;
    for (int i = 0; i < chunk; ++i) {
        int idx = base + i;
        if (idx < A) {
            rowptr[idx] = running;
            running += counts[idx];
            counts[idx] = 0;
        }
    }
    if (tid == SCAN_T - 1) rowptr[A] = lds[SCAN_T - 1];
}

// scatter: ONE 16B write per edge {dx,dy,dz, n-as-float-bits}
__global__ void csr_fill(const int* __restrict__ nl, const int* __restrict__ rowptr,
                         int* __restrict__ cursor,
                         const float* __restrict__ cart,
                         const float* __restrict__ shifts,
                         float4* __restrict__ geom,
                         int E)
{
    int e = blockIdx.x * blockDim.x + threadIdx.x;
    if (e >= E) return;
    int c = nl[e];
    int n = nl[E + e];
    float dx = cart[3*c+0] - cart[3*n+0] - shifts[3*e+0];
    float dy = cart[3*c+1] - cart[3*n+1] - shifts[3*e+1];
    float dz = cart[3*c+2] - cart[3*n+2] - shifts[3*e+2];
    int ofs  = atomicAdd(&cursor[c], 1);
    int slot = rowptr[c] + ofs;
    geom[slot] = make_float4(dx, dy, dz, __int_as_float(n));
}

// slot-major: contiguous read of geom, contiguous write of fc-folded gaussians
__global__ void gauss_k(const float4* __restrict__ geom,
                        const int* __restrict__ species,
                        const float* __restrict__ g_rs,
                        const float* __restrict__ g_inta,
                        const float* __restrict__ g_par,
                        float4* __restrict__ gauss,   // [2E] = [E][8] floats
                        int E)
{
    __shared__ float s_rs[32], s_in[32], s_pa[32];
    int tid = threadIdx.x;
    if (tid < 32) {
        s_rs[tid] = g_rs[tid];
        s_in[tid] = g_inta[tid];
        s_pa[tid] = g_par[tid];
    }
    __syncthreads();
    int s = blockIdx.x * blockDim.x + tid;
    if (s >= E) return;
    float4 G = geom[s];
    float r = sqrtf(G.x*G.x + G.y*G.y + G.z*G.z);
    float fcb = 0.5f * cosf(r * 0.6283185307179586f) + 0.5f;   // pi/5
    float fc  = fcb * fcb;
    int sb = species[__float_as_int(G.w)] * NW;
    float g[NW];
    #pragma unroll
    for (int w = 0; w < NW; ++w) {
        float dr = r - s_rs[sb + w];
        g[w] = __expf(-s_in[sb + w] * dr * dr) * s_pa[sb + w] * fc;
    }
    gauss[2*s+0] = make_float4(g[0], g[1], g[2], g[3]);
    gauss[2*s+1] = make_float4(g[4], g[5], g[6], g[7]);
}

// ---------------- fused per-atom pass (+ optional MLP epilogue) ----------------
// Transposed LDS tiles -> inner loop = 2x ds_read_b128 + 4 FMA per 4 edges.
template<bool HASOUT, bool MLP>
__global__ __launch_bounds__(128)
void atom_pass(const float4* __restrict__ geom,
               const float* __restrict__ gauss8,   // [E*8], fc-folded
               const int* __restrict__ rowptr,
               const float* __restrict__ outp_in,  // [A,24] if HASOUT
               const float* __restrict__ w1, const float* __restrict__ b1,
               const float* __restrict__ w2, const float* __restrict__ b2,
               float* __restrict__ out,            // [A,24]: mlp out (MLP) or density
               int A)
{
    __shared__ __align__(16) float ls_ang[PORI][CHP];
    __shared__ __align__(16) float ls_og[NATOM_FEAT][CHP];
    __shared__ float orb_s[PORI * NW];
    __shared__ float dvec[NATOM_FEAT];
    __shared__ float tvec[HID];

    int tid = threadIdx.x;
    int a = blockIdx.x;
    int s0 = rowptr[a], s1 = rowptr[a+1];

    int f = tid;                     // f = p*8 + w, valid for f < 104
    int p = f >> 3, w = f & 7;
    int ip = (p == 0) ? 0 : ((p < 4) ? 1 : 2);
    int ogidx = ip * NW + w;
    float acc = 0.0f;

    for (int s = s0; s < s1; s += CH) {
        int m  = min(CH, s1 - s);
        int mm = (m + 3) & ~3;       // pad to multiple of 4 for b128 reads
        if (tid < mm) {
            float ax = 0.0f, ay = 0.0f, az = 0.0f;
            if (tid < m) { float4 G = geom[s + tid]; ax = G.x; ay = G.y; az = G.z; }
            ls_ang[0][tid]  = 1.0f;
            ls_ang[1][tid]  = ax;    ls_ang[2][tid]  = ay;    ls_ang[3][tid]  = az;
            ls_ang[4][tid]  = ax*ax; ls_ang[5][tid]  = ax*ay; ls_ang[6][tid]  = ax*az;
            ls_ang[7][tid]  = ay*ax; ls_ang[8][tid]  = ay*ay; ls_ang[9][tid]  = ay*az;
            ls_ang[10][tid] = az*ax; ls_ang[11][tid] = az*ay; ls_ang[12][tid] = az*az;
        }
        for (int idx = tid; idx < mm * NATOM_FEAT; idx += 128) {
            int j = idx / NATOM_FEAT;          // const divisor -> magic mul
            int c = idx - j * NATOM_FEAT;
            float gg = 0.0f;
            if (j < m) {
                gg = gauss8[(size_t)(s + j) * NW + (c & 7)];
                if (HASOUT) {
                    int n = __float_as_int(geom[s + j].w);   // L1-hit broadcast
                    gg *= outp_in[(size_t)n * NATOM_FEAT + c];
                }
            }
            ls_og[c][j] = gg;                  // pad columns zeroed -> safe
        }
        __syncthreads();
        if (f < PORI * NW) {
            const float4* ap = (const float4*)&ls_ang[p][0];
            const float4* op = (const float4*)&ls_og[ogidx][0];
            int mm4 = mm >> 2;
            for (int j4 = 0; j4 < mm4; ++j4) {
                float4 av = ap[j4];
                float4 ov = op[j4];
                acc += av.x * ov.x;
                acc += av.y * ov.y;
                acc += av.z * ov.z;
                acc += av.w * ov.w;
            }
        }
        __syncthreads();
    }

    if (f < PORI * NW) orb_s[f] = acc * acc;
    __syncthreads();

    if (tid < NATOM_FEAT) {
        int i = tid >> 3, ww = tid & 7;
        float sum;
        if (i == 0) {
            sum = orb_s[ww];
        } else if (i == 1) {
            sum = orb_s[NW + ww] + orb_s[2*NW + ww] + orb_s[3*NW + ww];
        } else {
            sum = 0.0f;
            #pragma unroll
            for (int q = 4; q < PORI; ++q) sum += orb_s[q*NW + ww];
        }
        if (MLP) dvec[tid] = sum;
        else     out[(size_t)a * NATOM_FEAT + tid] = sum;
    }

    if (MLP) {
        __syncthreads();
        // phase B: 128 lanes = 128 hidden units; w1 reads coalesced + L1/L2 cached
        float hacc = b1[tid];
        #pragma unroll
        for (int j = 0; j < NATOM_FEAT; ++j) hacc += dvec[j] * w1[j * HID + tid];
        float e = __expf(2.0f * hacc);
        tvec[tid] = 1.0f - 2.0f / (e + 1.0f);   // tanh, saturates correctly
        __syncthreads();
        // phase C: 24 lanes = 24 outputs
        if (tid < NATOM_FEAT) {
            float o = b2[tid];
            #pragma unroll 8
            for (int h = 0; h < HID; ++h) o += tvec[h] * w2[h * NATOM_FEAT + tid];
            out[(size_t)a * NATOM_FEAT + tid] = o;
        }
    }
}

extern "C" void kernel_launch(void* const* d_in, const int* in_sizes, int n_in,
                              void* d_out, int out_size, void* d_ws, size_t ws_size,
                              hipStream_t stream)
{
    const float* cart    = (const float*)d_in[0];
    const int*   nl      = (const int*)d_in[1];
    const float* shifts  = (const float*)d_in[2];
    const int*   species = (const int*)d_in[3];
    const float* rs      = (const float*)d_in[4];
    const float* inta    = (const float*)d_in[5];
    const float* params  = (const float*)d_in[6];
    const float* w1_0 = (const float*)d_in[7];
    const float* b1_0 = (const float*)d_in[8];
    const float* w2_0 = (const float*)d_in[9];
    const float* b2_0 = (const float*)d_in[10];
    const float* w1_1 = (const float*)d_in[11];
    const float* b1_1 = (const float*)d_in[12];
    const float* w2_1 = (const float*)d_in[13];
    const float* b2_1 = (const float*)d_in[14];

    const int A = in_sizes[0] / 3;
    const int E = in_sizes[1] / 2;

    // workspace layout — 16B-aligned arrays first
    char* ws = (char*)d_ws;
    float4* geom  = (float4*)ws;              ws += (size_t)E * 16;
    float4* gauss = (float4*)ws;              ws += (size_t)E * 32;
    int*   counts = (int*)ws;                 ws += (size_t)A * 4;
    int*   rowptr = (int*)ws;                 ws += (size_t)(A + 1) * 4;
    float* outpA  = (float*)ws;               ws += (size_t)A * NATOM_FEAT * 4;
    float* outpB  = (float*)ws;               ws += (size_t)A * NATOM_FEAT * 4;
    float* dout   = (float*)d_out;

    const int BLK = 256;
    const int gridE = (E + BLK - 1) / BLK;
    const int gridA = (A + BLK - 1) / BLK;

    // ---- CSR build + per-edge precompute (once) ----
    zero_k<<<gridA, BLK, 0, stream>>>(counts, A);
    csr_count<<<gridE, BLK, 0, stream>>>(nl, counts, E);
    csr_scan<<<1, SCAN_T, 0, stream>>>(counts, rowptr, A);
    csr_fill<<<gridE, BLK, 0, stream>>>(nl, rowptr, counts, cart, shifts, geom, E);
    gauss_k<<<gridE, BLK, 0, stream>>>(geom, species, rs, inta, params, gauss, E);

    // ---- pass 0 (+ MLP0) -> outpA ----
    atom_pass<false, true><<<A, 128, 0, stream>>>(geom, (const float*)gauss, rowptr,
                                                  nullptr, w1_0, b1_0, w2_0, b2_0, outpA, A);
    // ---- pass 1 (+ MLP1) -> outpB ----
    atom_pass<true, true><<<A, 128, 0, stream>>>(geom, (const float*)gauss, rowptr,
                                                 outpA, w1_1, b1_1, w2_1, b2_1, outpB, A);
    // ---- pass 2 (density only) -> d_out ----
    atom_pass<true, false><<<A, 128, 0, stream>>>(geom, (const float*)gauss, rowptr,
                                                  outpB, nullptr, nullptr, nullptr, nullptr, dout, A);
}

// Round 9
// 218.883 us; speedup vs baseline: 1.0894x; 1.0894x over previous
//
#include <hip/hip_runtime.h>
#include <math.h>

#define NATOM_FEAT 24   // IPSIN * NWAVE = 3*8
#define PORI 13
#define NW 8
#define HID 128
#define CH 64           // edges staged per LDS chunk
#define SCAN_T 1024

__global__ void zero_k(int* __restrict__ p, int n)
{
    int i = blockIdx.x * blockDim.x + threadIdx.x;
    if (i < n) p[i] = 0;
}

// ---------------- CSR build ----------------
__global__ void csr_count(const int* __restrict__ nl, int* __restrict__ counts, int E)
{
    int e = blockIdx.x * blockDim.x + threadIdx.x;
    if (e < E) atomicAdd(&counts[nl[e]], 1);
}

// scan counts -> rowptr, re-zero counts (reused as fill cursor)
__global__ void csr_scan(int* __restrict__ counts, int* __restrict__ rowptr, int A)
{
    __shared__ int lds[SCAN_T];
    int tid = threadIdx.x;
    int chunk = (A + SCAN_T - 1) / SCAN_T;
    int base = tid * chunk;
    int own = 0;
    for (int i = 0; i < chunk; ++i) {
        int idx = base + i;
        if (idx < A) own += counts[idx];
    }
    lds[tid] = own;
    __syncthreads();
    for (int off = 1; off < SCAN_T; off <<= 1) {
        int v = (tid >= off) ? lds[tid - off] : 0;
        __syncthreads();
        lds[tid] += v;
        __syncthreads();
    }
    int running = lds[tid] - own;
    for (int i = 0; i < chunk; ++i) {
        int idx = base + i;
        if (idx < A) {
            rowptr[idx] = running;
            running += counts[idx];
            counts[idx] = 0;
        }
    }
    if (tid == SCAN_T - 1) rowptr[A] = lds[SCAN_T - 1];
}

// scatter: ONE 16B write per edge {dx,dy,dz, n-as-float-bits}
__global__ void csr_fill(const int* __restrict__ nl, const int* __restrict__ rowptr,
                         int* __restrict__ cursor,
                         const float* __restrict__ cart,
                         const float* __restrict__ shifts,
                         float4* __restrict__ geom,
                         int E)
{
    int e = blockIdx.x * blockDim.x + threadIdx.x;
    if (e >= E) return;
    int c = nl[e];
    int n = nl[E + e];
    float dx = cart[3*c+0] - cart[3*n+0] - shifts[3*e+0];
    float dy = cart[3*c+1] - cart[3*n+1] - shifts[3*e+1];
    float dz = cart[3*c+2] - cart[3*n+2] - shifts[3*e+2];
    int ofs  = atomicAdd(&cursor[c], 1);
    int slot = rowptr[c] + ofs;
    geom[slot] = make_float4(dx, dy, dz, __int_as_float(n));
}

// slot-major: contiguous read of geom, contiguous write of fc-folded gaussians
__global__ void gauss_k(const float4* __restrict__ geom,
                        const int* __restrict__ species,
                        const float* __restrict__ g_rs,
                        const float* __restrict__ g_inta,
                        const float* __restrict__ g_par,
                        float4* __restrict__ gauss,   // [2E] = [E][8] floats
                        int E)
{
    __shared__ float s_rs[32], s_in[32], s_pa[32];
    int tid = threadIdx.x;
    if (tid < 32) {
        s_rs[tid] = g_rs[tid];
        s_in[tid] = g_inta[tid];
        s_pa[tid] = g_par[tid];
    }
    __syncthreads();
    int s = blockIdx.x * blockDim.x + tid;
    if (s >= E) return;
    float4 G = geom[s];
    float r = sqrtf(G.x*G.x + G.y*G.y + G.z*G.z);
    float fcb = 0.5f * cosf(r * 0.6283185307179586f) + 0.5f;   // pi/5
    float fc  = fcb * fcb;
    int sb = species[__float_as_int(G.w)] * NW;
    float g[NW];
    #pragma unroll
    for (int w = 0; w < NW; ++w) {
        float dr = r - s_rs[sb + w];
        g[w] = __expf(-s_in[sb + w] * dr * dr) * s_pa[sb + w] * fc;
    }
    gauss[2*s+0] = make_float4(g[0], g[1], g[2], g[3]);
    gauss[2*s+1] = make_float4(g[4], g[5], g[6], g[7]);
}

// ---------------- fused per-atom pass (+ optional MLP epilogue) ----------------
// [edge][feat] LDS layout: inner-loop reads are bank-conflict-free broadcasts.
template<bool HASOUT, bool MLP>
__global__ __launch_bounds__(128)
void atom_pass(const float4* __restrict__ geom,
               const float* __restrict__ gauss8,   // [E*8], fc-folded
               const int* __restrict__ rowptr,
               const float* __restrict__ outp_in,  // [A,24] if HASOUT
               const float* __restrict__ w1, const float* __restrict__ b1,
               const float* __restrict__ w2, const float* __restrict__ b2,
               float* __restrict__ out,            // [A,24]: mlp out (MLP) or density
               int A)
{
    __shared__ float ls_ang[CH][PORI];        // stride 13 (odd) -> conflict-free
    __shared__ float ls_og[CH][NATOM_FEAT];
    __shared__ float orb_s[PORI * NW];
    __shared__ float dvec[NATOM_FEAT];
    __shared__ float tvec[HID];

    int tid = threadIdx.x;
    int a = blockIdx.x;
    int s0 = rowptr[a], s1 = rowptr[a+1];

    int f = tid;                     // f = p*8 + w, valid for f < 104
    int p = f >> 3, w = f & 7;
    int ip = (p == 0) ? 0 : ((p < 4) ? 1 : 2);
    int ogidx = ip * NW + w;
    float acc = 0.0f;

    for (int s = s0; s < s1; s += CH) {
        int m = min(CH, s1 - s);
        if (tid < m) {
            float4 G = geom[s + tid];
            float ax = G.x, ay = G.y, az = G.z;
            ls_ang[tid][0]  = 1.0f;
            ls_ang[tid][1]  = ax;    ls_ang[tid][2]  = ay;    ls_ang[tid][3]  = az;
            ls_ang[tid][4]  = ax*ax; ls_ang[tid][5]  = ax*ay; ls_ang[tid][6]  = ax*az;
            ls_ang[tid][7]  = ay*ax; ls_ang[tid][8]  = ay*ay; ls_ang[tid][9]  = ay*az;
            ls_ang[tid][10] = az*ax; ls_ang[tid][11] = az*ay; ls_ang[tid][12] = az*az;
        }
        for (int idx = tid; idx < m * NATOM_FEAT; idx += 128) {
            int j = idx / NATOM_FEAT;          // const divisor -> magic mul
            int c = idx - j * NATOM_FEAT;
            float gg = gauss8[(size_t)(s + j) * NW + (c & 7)];
            if (HASOUT) {
                int n = __float_as_int(geom[s + j].w);   // L1-hit (line staged above)
                gg *= outp_in[(size_t)n * NATOM_FEAT + c];
            }
            ls_og[j][c] = gg;
        }
        __syncthreads();
        if (f < PORI * NW) {
            #pragma unroll 4
            for (int j = 0; j < m; ++j)
                acc += ls_ang[j][p] * ls_og[j][ogidx];
        }
        __syncthreads();
    }

    if (f < PORI * NW) orb_s[f] = acc * acc;
    __syncthreads();

    if (tid < NATOM_FEAT) {
        int i = tid >> 3, ww = tid & 7;
        float sum;
        if (i == 0) {
            sum = orb_s[ww];
        } else if (i == 1) {
            sum = orb_s[NW + ww] + orb_s[2*NW + ww] + orb_s[3*NW + ww];
        } else {
            sum = 0.0f;
            #pragma unroll
            for (int q = 4; q < PORI; ++q) sum += orb_s[q*NW + ww];
        }
        if (MLP) dvec[tid] = sum;
        else     out[(size_t)a * NATOM_FEAT + tid] = sum;
    }

    if (MLP) {
        __syncthreads();
        // phase B: 128 lanes = 128 hidden units; w1 reads coalesced + L1/L2 cached
        float hacc = b1[tid];
        #pragma unroll
        for (int j = 0; j < NATOM_FEAT; ++j) hacc += dvec[j] * w1[j * HID + tid];
        float e = __expf(2.0f * hacc);
        tvec[tid] = 1.0f - 2.0f / (e + 1.0f);   // tanh, saturates correctly
        __syncthreads();
        // phase C: 24 lanes = 24 outputs
        if (tid < NATOM_FEAT) {
            float o = b2[tid];
            #pragma unroll 8
            for (int h = 0; h < HID; ++h) o += tvec[h] * w2[h * NATOM_FEAT + tid];
            out[(size_t)a * NATOM_FEAT + tid] = o;
        }
    }
}

extern "C" void kernel_launch(void* const* d_in, const int* in_sizes, int n_in,
                              void* d_out, int out_size, void* d_ws, size_t ws_size,
                              hipStream_t stream)
{
    const float* cart    = (const float*)d_in[0];
    const int*   nl      = (const int*)d_in[1];
    const float* shifts  = (const float*)d_in[2];
    const int*   species = (const int*)d_in[3];
    const float* rs      = (const float*)d_in[4];
    const float* inta    = (const float*)d_in[5];
    const float* params  = (const float*)d_in[6];
    const float* w1_0 = (const float*)d_in[7];
    const float* b1_0 = (const float*)d_in[8];
    const float* w2_0 = (const float*)d_in[9];
    const float* b2_0 = (const float*)d_in[10];
    const float* w1_1 = (const float*)d_in[11];
    const float* b1_1 = (const float*)d_in[12];
    const float* w2_1 = (const float*)d_in[13];
    const float* b2_1 = (const float*)d_in[14];

    const int A = in_sizes[0] / 3;
    const int E = in_sizes[1] / 2;

    // workspace layout — 16B-aligned arrays first
    char* ws = (char*)d_ws;
    float4* geom  = (float4*)ws;              ws += (size_t)E * 16;
    float4* gauss = (float4*)ws;              ws += (size_t)E * 32;
    int*   counts = (int*)ws;                 ws += (size_t)A * 4;
    int*   rowptr = (int*)ws;                 ws += (size_t)(A + 1) * 4;
    float* outpA  = (float*)ws;               ws += (size_t)A * NATOM_FEAT * 4;
    float* outpB  = (float*)ws;               ws += (size_t)A * NATOM_FEAT * 4;
    float* dout   = (float*)d_out;

    const int BLK = 256;
    const int gridE = (E + BLK - 1) / BLK;
    const int gridA = (A + BLK - 1) / BLK;

    // ---- CSR build + per-edge precompute (once) ----
    zero_k<<<gridA, BLK, 0, stream>>>(counts, A);
    csr_count<<<gridE, BLK, 0, stream>>>(nl, counts, E);
    csr_scan<<<1, SCAN_T, 0, stream>>>(counts, rowptr, A);
    csr_fill<<<gridE, BLK, 0, stream>>>(nl, rowptr, counts, cart, shifts, geom, E);
    gauss_k<<<gridE, BLK, 0, stream>>>(geom, species, rs, inta, params, gauss, E);

    // ---- pass 0 (+ MLP0) -> outpA ----
    atom_pass<false, true><<<A, 128, 0, stream>>>(geom, (const float*)gauss, rowptr,
                                                  nullptr, w1_0, b1_0, w2_0, b2_0, outpA, A);
    // ---- pass 1 (+ MLP1) -> outpB ----
    atom_pass<true, true><<<A, 128, 0, stream>>>(geom, (const float*)gauss, rowptr,
                                                 outpA, w1_1, b1_1, w2_1, b2_1, outpB, A);
    // ---- pass 2 (density only) -> d_out ----
    atom_pass<true, false><<<A, 128, 0, stream>>>(geom, (const float*)gauss, rowptr,
                                                  outpB, nullptr, nullptr, nullptr, nullptr, dout, A);
}